// Round 10
// baseline (4427.657 us; speedup 1.0000x reference)
//
#include <hip/hip_runtime.h>
#include <hip/hip_bf16.h>

typedef __hip_bfloat16 bf16;
typedef float fx2 __attribute__((ext_vector_type(2)));

#define NL 4096      // L leaves
#define NH 128       // H hidden
#define NE 256       // E embed
#define NT 64        // T tags
#define NNODE 8191   // N = 2L-1
#define NDEPTH 12    // D = log2(L)

// converted f32 weights, offsets into wf[] (floats)
#define OF_WIH   0
#define OF_WHH   131072
#define OF_BIH   196608
#define OF_BHH   197120
#define OF_WP2H  197632
#define OF_BP2H  230400
#define OF_WUNI  230528
#define OF_BUNI  238720
#define OF_WEDGE 238784
#define OF_BEDGE 1287360
#define WF_TOTAL 1291456

__device__ __forceinline__ float b2f(bf16 x) { return __bfloat162float(x); }
__device__ __forceinline__ float blo(unsigned u) { return __uint_as_float(u << 16); }
__device__ __forceinline__ float bhi(unsigned u) { return __uint_as_float(u & 0xffff0000u); }

// ------------------------------------------------ dtype detection
__global__ void detect_kernel(const void* __restrict__ wedge_raw, int* __restrict__ flag) {
  __shared__ int cnt_sh[256];
  const unsigned short* p = (const unsigned short*)wedge_raw;
  int c = 0;
  for (int i = threadIdx.x; i < 32768; i += 256) {
    float v = __uint_as_float(((unsigned)p[2 * i]) << 16);
    if (fabsf(v) > 4.f) c++;
  }
  cnt_sh[threadIdx.x] = c;
  __syncthreads();
  for (int s = 128; s > 0; s >>= 1) {
    if (threadIdx.x < s) cnt_sh[threadIdx.x] += cnt_sh[threadIdx.x + s];
    __syncthreads();
  }
  if (threadIdx.x == 0) *flag = cnt_sh[0];   // >100 => inputs are f32
}

// ------------------------------------------------ convert all weights -> f32 in ws
__global__ void convert_kernel(const void* s0, const void* s1, const void* s2, const void* s3,
                               const void* s4, const void* s5, const void* s6, const void* s7,
                               const void* s8, const void* s9,
                               const int* __restrict__ flag, float* __restrict__ wf) {
  int i = blockIdx.x * 256 + threadIdx.x;
  if (i >= WF_TOTAL) return;
  const void* src; int local;
  if      (i < OF_WHH)   { src = s0; local = i; }
  else if (i < OF_BIH)   { src = s1; local = i - OF_WHH; }
  else if (i < OF_BHH)   { src = s2; local = i - OF_BIH; }
  else if (i < OF_WP2H)  { src = s3; local = i - OF_BHH; }
  else if (i < OF_BP2H)  { src = s4; local = i - OF_WP2H; }
  else if (i < OF_WUNI)  { src = s5; local = i - OF_BP2H; }
  else if (i < OF_BUNI)  { src = s6; local = i - OF_WUNI; }
  else if (i < OF_WEDGE) { src = s7; local = i - OF_BUNI; }
  else if (i < OF_BEDGE) { src = s8; local = i - OF_WEDGE; }
  else                   { src = s9; local = i - OF_BEDGE; }
  bool isf32 = (*flag) > 100;
  wf[i] = isf32 ? ((const float*)src)[local] : b2f(((const bf16*)src)[local]);
}

// ------------------------------------------------ G1 = emb[tok]@W_ih^T + b_ih + b_hh
__global__ __launch_bounds__(512) void g1_kernel(const int* __restrict__ tokens,
                                                 const void* __restrict__ emb_raw,
                                                 const int* __restrict__ flag,
                                                 const float* __restrict__ wf,
                                                 float* __restrict__ G1) {
  __shared__ __attribute__((aligned(16))) float xs[8 * NE];
  const bool isf32 = (*flag) > 100;
  const int t0 = blockIdx.x * 8;
  for (int q = threadIdx.x; q < 8 * NE; q += 512) {
    int tok = q >> 8, e = q & 255;
    size_t off = (size_t)tokens[t0 + tok] * NE + e;
    xs[q] = isf32 ? ((const float*)emb_raw)[off] : b2f(((const bf16*)emb_raw)[off]);
  }
  __syncthreads();
  const int r = threadIdx.x;                 // gate row 0..511
  const float bias = wf[OF_BIH + r] + wf[OF_BHH + r];
  float acc[8];
#pragma unroll
  for (int k = 0; k < 8; ++k) acc[k] = bias;
  const float4* W4 = (const float4*)(wf + OF_WIH + (size_t)r * NE);
#pragma unroll 8
  for (int j = 0; j < 64; ++j) {
    float4 wv = W4[j];
#pragma unroll
    for (int tok = 0; tok < 8; ++tok) {
      float4 xv = ((const float4*)(xs + tok * NE))[j];   // wave-uniform broadcast
      acc[tok] += wv.x * xv.x + wv.y * xv.y + wv.z * xv.z + wv.w * xv.w;
    }
  }
#pragma unroll
  for (int tok = 0; tok < 8; ++tok) G1[(size_t)(t0 + tok) * 512 + r] = acc[tok];
}

// ------------------------------------------------ sequential LSTM, 1 block, 512 threads
// R9 falsified the bandwidth model (halving weight bytes changed nothing);
// the ~2000 cyc/step invariant is the sync skeleton: g_sh write + barrier +
// 25%-occupancy phase B (g_sh read latency + serial exp) + second barrier.
// This version keeps the gates IN-WAVE: thread r computes gate row
// orow=(r&3)*128+(r>>2), so the 4 gates of h-row j=r>>2 live in 4 adjacent
// lanes; a 3-shuffle all-gather + 8 cndmask replaces the g_sh round-trip;
// phase B runs redundantly in all 512 threads; h_sh is double-buffered so
// there is ONE barrier per step (write buf p^1 while others read buf p;
// barrier orders step t's reads of p before step t+1's writes of p).
__global__ __launch_bounds__(512) void lstm_kernel(const float* __restrict__ wf,
                                                   const void* __restrict__ whh_raw,
                                                   const int* __restrict__ flag,
                                                   const float* __restrict__ G1,
                                                   float* __restrict__ hidden) {
  const int r = threadIdx.x;                 // 0..511
  const int q = r & 3;                       // gate index (i,f,g,o)
  const int j = r >> 2;                      // h-row 0..127
  const int orow = q * 128 + j;              // standard gate-row index
  __shared__ __attribute__((aligned(16))) float h_sh[2][NH];
  const bool isf32 = (*flag) > 100;

  float c = 0.f;
  if (r < NH) h_sh[0][r] = 0.f;
  __syncthreads();
  float gnext = G1[orow];                    // prefetch t=0

  if (!isf32) {
    // ---- bf16 weight stream: 256 B/row, 16 x uint4 (8 bf16 each) ----
    const uint4* Wh = (const uint4*)((const unsigned short*)whh_raw + (size_t)orow * NH);
    for (int t = 0; t < NL; ++t) {
      float gcur = gnext;
      if (t + 1 < NL) gnext = G1[(size_t)(t + 1) * 512 + orow];
      const float4* h4 = (const float4*)h_sh[t & 1];
      float* hn = h_sh[(t & 1) ^ 1];
      fx2 a0 = {0.f, 0.f}, a1 = {0.f, 0.f}, a2 = {0.f, 0.f}, a3 = {0.f, 0.f};
#pragma unroll
      for (int i = 0; i < 16; ++i) {         // 8 weights per iteration
        uint4 wq = Wh[i];
        float4 hA = h4[2 * i], hB = h4[2 * i + 1];   // wave-uniform broadcasts
        fx2 w01, w23, w45, w67, e01, e23, e45, e67;
        w01.x = blo(wq.x); w01.y = bhi(wq.x);
        w23.x = blo(wq.y); w23.y = bhi(wq.y);
        w45.x = blo(wq.z); w45.y = bhi(wq.z);
        w67.x = blo(wq.w); w67.y = bhi(wq.w);
        e01.x = hA.x; e01.y = hA.y; e23.x = hA.z; e23.y = hA.w;
        e45.x = hB.x; e45.y = hB.y; e67.x = hB.z; e67.y = hB.w;
        a0 += w01 * e01;
        a1 += w23 * e23;
        a2 += w45 * e45;
        a3 += w67 * e67;
      }
      float gown = gcur + (a0.x + a0.y) + (a1.x + a1.y) + (a2.x + a2.y) + (a3.x + a3.y);
      // 4-lane all-gather of the gate values (lanes 4j..4j+3 hold gates of row j)
      float x1 = __shfl_xor(gown, 1);
      float x2 = __shfl_xor(gown, 2);
      float x3 = __shfl_xor(x1, 2);
      bool b0 = (q & 1) != 0, b1 = (q & 2) != 0;
      float t01 = b0 ? x1 : gown;
      float t23 = b0 ? x3 : x2;
      float f01 = b0 ? gown : x1;
      float f23 = b0 ? x2 : x3;
      float iv = b1 ? t23 : t01;
      float fv = b1 ? f23 : f01;
      float gv = b1 ? t01 : t23;
      float ov = b1 ? f01 : f23;
      float si = 1.f / (1.f + __expf(-iv));
      float sf = 1.f / (1.f + __expf(-fv));
      float tg = 1.f - 2.f / (__expf(2.f * gv) + 1.f);
      float so = 1.f / (1.f + __expf(-ov));
      c = sf * c + si * tg;                  // replicated x4 per row-group
      float hh = so * (1.f - 2.f / (__expf(2.f * c) + 1.f));
      if (q == 0) {
        hn[j] = hh;
        hidden[(size_t)(NL - 1 + t) * NH + j] = hh;   // leaf node L-1+t
      }
      __syncthreads();                       // single barrier per step
    }
  } else {
    // ---- f32 weight stream (same structure) ----
    const float4* Wrow = (const float4*)(wf + OF_WHH + (size_t)orow * NH);   // 32 quads
    for (int t = 0; t < NL; ++t) {
      float gcur = gnext;
      if (t + 1 < NL) gnext = G1[(size_t)(t + 1) * 512 + orow];
      const float4* h4 = (const float4*)h_sh[t & 1];
      float* hn = h_sh[(t & 1) ^ 1];
      fx2 a0 = {0.f, 0.f}, a1 = {0.f, 0.f}, a2 = {0.f, 0.f}, a3 = {0.f, 0.f};
#pragma unroll
      for (int i = 0; i < 16; ++i) {
        float4 w0 = Wrow[2 * i], w1 = Wrow[2 * i + 1];
        float4 hA = h4[2 * i], hB = h4[2 * i + 1];
        fx2 u0, u1, u2, u3, e0, e1, e2, e3;
        u0.x = w0.x; u0.y = w0.y; u1.x = w0.z; u1.y = w0.w;
        u2.x = w1.x; u2.y = w1.y; u3.x = w1.z; u3.y = w1.w;
        e0.x = hA.x; e0.y = hA.y; e1.x = hA.z; e1.y = hA.w;
        e2.x = hB.x; e2.y = hB.y; e3.x = hB.z; e3.y = hB.w;
        a0 += u0 * e0;
        a1 += u1 * e1;
        a2 += u2 * e2;
        a3 += u3 * e3;
      }
      float gown = gcur + (a0.x + a0.y) + (a1.x + a1.y) + (a2.x + a2.y) + (a3.x + a3.y);
      float x1 = __shfl_xor(gown, 1);
      float x2 = __shfl_xor(gown, 2);
      float x3 = __shfl_xor(x1, 2);
      bool b0 = (q & 1) != 0, b1 = (q & 2) != 0;
      float t01 = b0 ? x1 : gown;
      float t23 = b0 ? x3 : x2;
      float f01 = b0 ? gown : x1;
      float f23 = b0 ? x2 : x3;
      float iv = b1 ? t23 : t01;
      float fv = b1 ? f23 : f01;
      float gv = b1 ? t01 : t23;
      float ov = b1 ? f01 : f23;
      float si = 1.f / (1.f + __expf(-iv));
      float sf = 1.f / (1.f + __expf(-fv));
      float tg = 1.f - 2.f / (__expf(2.f * gv) + 1.f);
      float so = 1.f / (1.f + __expf(-ov));
      c = sf * c + si * tg;
      float hh = so * (1.f - 2.f / (__expf(2.f * c) + 1.f));
      if (q == 0) {
        hn[j] = hh;
        hidden[(size_t)(NL - 1 + t) * NH + j] = hh;
      }
      __syncthreads();
    }
  }
}

// ------------------------------------------------ one tree level: pair -> parent hidden
__global__ void p2h_kernel(const float* __restrict__ wf, float* __restrict__ hidden, int base) {
  int node = base + blockIdx.x;
  int j = threadIdx.x;                       // 128
  __shared__ __attribute__((aligned(16))) float pr[2 * NH];
  const float* hl = hidden + (size_t)(2 * node + 1) * NH;  // children contiguous
  pr[j] = hl[j];
  pr[j + NH] = hl[j + NH];
  __syncthreads();
  float acc = wf[OF_BP2H + j];
  const float4* W4 = (const float4*)(wf + OF_WP2H + (size_t)j * 2 * NH);
  const float4* p4 = (const float4*)pr;
#pragma unroll 16
  for (int q = 0; q < 64; ++q) {
    float4 u = W4[q], x = p4[q];
    acc += u.x * x.x + u.y * x.y + u.z * x.z + u.w * x.w;
  }
  hidden[(size_t)node * NH + j] = acc;
}

// ------------------------------------------------ unary = hidden@W_uni^T + b; zero f2n[0]
__global__ void unary_kernel(const float* __restrict__ wf, const float* __restrict__ hidden,
                             float* __restrict__ unary, float* __restrict__ f2n) {
  int node = blockIdx.x;
  int ct = threadIdx.x;                      // 64
  __shared__ __attribute__((aligned(16))) float hs[NH];
  hs[ct] = hidden[(size_t)node * NH + ct];
  hs[ct + 64] = hidden[(size_t)node * NH + 64 + ct];
  __syncthreads();
  float acc = wf[OF_BUNI + ct];
  const float4* W4 = (const float4*)(wf + OF_WUNI + (size_t)ct * NH);
  const float4* h4 = (const float4*)hs;
#pragma unroll
  for (int q = 0; q < 32; ++q) {
    float4 u = W4[q], x = h4[q];
    acc += u.x * x.x + u.y * x.y + u.z * x.z + u.w * x.w;
  }
  unary[(size_t)node * NT + ct] = acc;
  if (node == 0) f2n[ct] = 0.f;              // root gets no top-factor message
}

// ------------------------------------------------ edge_fac GEMM: [8192,256]x[256,4096]
__global__ __launch_bounds__(256) void edge_kernel(const float* __restrict__ hidden,
                                                   const float* __restrict__ wf,
                                                   float* __restrict__ edge) {
  __shared__ __attribute__((aligned(16))) float As[32][132];  // [k][m]
  __shared__ __attribute__((aligned(16))) float Bs[32][132];  // [k][n]
  const int tid = threadIdx.x;
  const int nb = blockIdx.x;                 // 0..31 (N tile of 128)
  const int mb = blockIdx.y;                 // 0..63 (M tile of 128)
  const int tm = tid >> 4, tn = tid & 15;    // 16x16 threads, 8x8 micro (split 4+4)
  float acc[8][8];
#pragma unroll
  for (int i = 0; i < 8; ++i)
#pragma unroll
    for (int j = 0; j < 8; ++j) acc[i][j] = 0.f;
  const int sr = tid >> 1;                   // staging row 0..127
  const int sq = tid & 1;                    // which 16-k half
  for (int ch = 0; ch < 8; ++ch) {           // K chunks of 32
    {                                        // stage A
      int gm = mb * 128 + sr;
      const float* srcA = (ch < 4) ? hidden + (size_t)(gm >> 1) * NH + ch * 32
                                   : hidden + (size_t)(gm + 1) * NH + (ch - 4) * 32;
      bool ok = (gm < NNODE - 1);
#pragma unroll
      for (int i = 0; i < 4; ++i) {
        int kk = sq * 16 + i * 4;
        float4 v = ok ? *(const float4*)(srcA + kk) : make_float4(0.f, 0.f, 0.f, 0.f);
        As[kk + 0][sr] = v.x; As[kk + 1][sr] = v.y; As[kk + 2][sr] = v.z; As[kk + 3][sr] = v.w;
      }
    }
    {                                        // stage B
      int gn = nb * 128 + sr;                // < 4096 always
      const float* srcB = wf + OF_WEDGE + (size_t)gn * NE + ch * 32;
#pragma unroll
      for (int i = 0; i < 4; ++i) {
        int kk = sq * 16 + i * 4;
        float4 v = *(const float4*)(srcB + kk);
        Bs[kk + 0][sr] = v.x; Bs[kk + 1][sr] = v.y; Bs[kk + 2][sr] = v.z; Bs[kk + 3][sr] = v.w;
      }
    }
    __syncthreads();
#pragma unroll 8
    for (int kk = 0; kk < 32; ++kk) {
      float a[8], b[8];
      *(float4*)(a)     = *(const float4*)&As[kk][tm * 4];
      *(float4*)(a + 4) = *(const float4*)&As[kk][64 + tm * 4];
      *(float4*)(b)     = *(const float4*)&Bs[kk][tn * 4];
      *(float4*)(b + 4) = *(const float4*)&Bs[kk][64 + tn * 4];
#pragma unroll
      for (int i = 0; i < 8; ++i)
#pragma unroll
        for (int j = 0; j < 8; ++j) acc[i][j] += a[i] * b[j];
    }
    __syncthreads();
  }
  float bias[8];
#pragma unroll
  for (int j = 0; j < 8; ++j)
    bias[j] = wf[OF_BEDGE + nb * 128 + (j >> 2) * 64 + tn * 4 + (j & 3)];
#pragma unroll
  for (int i = 0; i < 8; ++i) {
    int gm = mb * 128 + (i >> 2) * 64 + tm * 4 + (i & 3);
    if (gm < NNODE - 1) {
      float* row = edge + (size_t)gm * 4096 + nb * 128;
      float4 o0, o1;
      o0.x = acc[i][0] + bias[0]; o0.y = acc[i][1] + bias[1];
      o0.z = acc[i][2] + bias[2]; o0.w = acc[i][3] + bias[3];
      o1.x = acc[i][4] + bias[4]; o1.y = acc[i][5] + bias[5];
      o1.z = acc[i][6] + bias[6]; o1.w = acc[i][7] + bias[7];
      *(float4*)(row + tn * 4) = o0;
      *(float4*)(row + 64 + tn * 4) = o1;
    }
  }
}

// ------------------------------------------------ upward level
__global__ void up_kernel(const float* __restrict__ unary, const float* __restrict__ edge,
                          float* __restrict__ v2f, float* __restrict__ f2p,
                          int base, int depth) {
  int node = base + blockIdx.x;
  int tid = threadIdx.x;                     // 64; tid = p (parent tag)
  __shared__ __attribute__((aligned(16))) float vs[NT];
  float vv = unary[(size_t)node * NT + tid];
  if (depth < NDEPTH)
    vv += f2p[(size_t)(2 * node + 1) * NT + tid] + f2p[(size_t)(2 * node + 2) * NT + tid];
  v2f[(size_t)node * NT + tid] = vv;
  vs[tid] = vv;
  __syncthreads();
  if (depth == 0) return;
  const float4* E4 = (const float4*)(edge + (size_t)(node - 1) * 4096 + tid * 64);
  const float4* v4 = (const float4*)vs;
  float x[NT];
#pragma unroll
  for (int q = 0; q < 16; ++q) {
    float4 e = E4[q], vq = v4[q];
    x[4 * q + 0] = e.x + vq.x; x[4 * q + 1] = e.y + vq.y;
    x[4 * q + 2] = e.z + vq.z; x[4 * q + 3] = e.w + vq.w;
  }
  float m = x[0];
#pragma unroll
  for (int i = 1; i < NT; ++i) m = fmaxf(m, x[i]);
  float s = 0.f;
#pragma unroll
  for (int i = 0; i < NT; ++i) s += __expf(x[i] - m);
  f2p[(size_t)node * NT + tid] = m + __logf(s);
}

// ------------------------------------------------ downward level
__global__ void down_kernel(const float* __restrict__ unary, const float* __restrict__ edge,
                            const float* __restrict__ f2p, float* __restrict__ f2n,
                            int base) {
  int node = base + blockIdx.x;
  int tid = threadIdx.x;                     // 64; tid = c (child tag)
  int par = (node - 1) >> 1;
  int sib = (node & 1) ? node + 1 : node - 1;
  __shared__ __attribute__((aligned(16))) float us[NT];
  us[tid] = unary[(size_t)par * NT + tid] + f2n[(size_t)par * NT + tid] +
            f2p[(size_t)sib * NT + tid];
  __syncthreads();
  float uu[NT];
  const float4* u4 = (const float4*)us;
#pragma unroll
  for (int q = 0; q < 16; ++q) {
    float4 t4 = u4[q];
    uu[4 * q] = t4.x; uu[4 * q + 1] = t4.y; uu[4 * q + 2] = t4.z; uu[4 * q + 3] = t4.w;
  }
  const float* E = edge + (size_t)(node - 1) * 4096 + tid;
  float x[NT];
#pragma unroll
  for (int p = 0; p < NT; ++p) x[p] = E[(size_t)p * 64] + uu[p];
  float m = x[0];
#pragma unroll
  for (int i = 1; i < NT; ++i) m = fmaxf(m, x[i]);
  float s = 0.f;
#pragma unroll
  for (int i = 0; i < NT; ++i) s += __expf(x[i] - m);
  f2n[(size_t)node * NT + tid] = m + __logf(s);
}

// ------------------------------------------------ beliefs -> postorder -> out (flag dtype)
__global__ void final_kernel(const float* __restrict__ v2f, const float* __restrict__ f2n,
                             const int* __restrict__ flag, void* __restrict__ out) {
  int node = blockIdx.x;
  int tid = threadIdx.x;                     // 64
  unsigned v = (unsigned)node + 1u;
  int d = 31 - __clz((int)v);
  int b0 = 0, S = NNODE;
  for (int b = d - 1; b >= 0; --b) {
    int sz = (S - 1) >> 1;
    if ((v >> b) & 1) b0 += sz;
    S = sz;
  }
  int pos = b0 + S - 1;
  float val = v2f[(size_t)node * NT + tid] + f2n[(size_t)node * NT + tid];
  if ((*flag) > 100) ((float*)out)[(size_t)pos * NT + tid] = val;
  else               ((bf16*)out)[(size_t)pos * NT + tid] = __float2bfloat16(val);
}

// ------------------------------------------------
extern "C" void kernel_launch(void* const* d_in, const int* in_sizes, int n_in,
                              void* d_out, int out_size, void* d_ws, size_t ws_size,
                              hipStream_t stream) {
  (void)in_sizes; (void)n_in; (void)out_size; (void)ws_size;
  const int* tokens = (const int*)d_in[0];

  // workspace layout (floats); ~160.3 MB total
  float* ws     = (float*)d_ws;
  int*   flag   = (int*)ws;                            // [16]
  float* wf     = ws + 16;                             // converted f32 weights
  float* hidden = wf + WF_TOTAL;                       // [8191][128]
  float* G1     = hidden + (size_t)NNODE * NH;         // [4096][512]
  float* unary  = G1 + (size_t)NL * 512;               // [8191][64]
  float* v2f    = unary + (size_t)NNODE * NT;          // [8191][64]
  float* f2p    = v2f + (size_t)NNODE * NT;            // [8191][64]
  float* f2n    = f2p + (size_t)NNODE * NT;            // [8191][64]
  float* edge   = f2n + (size_t)NNODE * NT;            // [8190][4096]

  detect_kernel<<<1, 256, 0, stream>>>(d_in[10], flag);
  convert_kernel<<<(WF_TOTAL + 255) / 256, 256, 0, stream>>>(
      d_in[2], d_in[3], d_in[4], d_in[5], d_in[6], d_in[7],
      d_in[8], d_in[9], d_in[10], d_in[11], flag, wf);
  g1_kernel<<<NL / 8, 512, 0, stream>>>(tokens, d_in[1], flag, wf, G1);
  lstm_kernel<<<1, 512, 0, stream>>>(wf, d_in[3], flag, G1, hidden);
  for (int d = NDEPTH - 1; d >= 0; --d)
    p2h_kernel<<<1 << d, 128, 0, stream>>>(wf, hidden, (1 << d) - 1);
  unary_kernel<<<NNODE, 64, 0, stream>>>(wf, hidden, unary, f2n);
  edge_kernel<<<dim3(32, 64), 256, 0, stream>>>(hidden, wf, edge);
  for (int d = NDEPTH; d >= 0; --d)
    up_kernel<<<1 << d, 64, 0, stream>>>(unary, edge, v2f, f2p, (1 << d) - 1, d);
  for (int d = 1; d <= NDEPTH; ++d)
    down_kernel<<<1 << d, 64, 0, stream>>>(unary, edge, f2p, f2n, (1 << d) - 1);
  final_kernel<<<NNODE, 64, 0, stream>>>(v2f, f2n, flag, d_out);
}

// Round 11
// 4019.246 us; speedup vs baseline: 1.1016x; 1.1016x over previous
//
#include <hip/hip_runtime.h>
#include <hip/hip_bf16.h>

typedef __hip_bfloat16 bf16;
typedef float fx2 __attribute__((ext_vector_type(2)));

#define NL 4096      // L leaves
#define NH 128       // H hidden
#define NE 256       // E embed
#define NT 64        // T tags
#define NNODE 8191   // N = 2L-1
#define NDEPTH 12    // D = log2(L)

// converted f32 weights, offsets into wf[] (floats)
#define OF_WIH   0
#define OF_WHH   131072
#define OF_BIH   196608
#define OF_BHH   197120
#define OF_WP2H  197632
#define OF_BP2H  230400
#define OF_WUNI  230528
#define OF_BUNI  238720
#define OF_WEDGE 238784
#define OF_BEDGE 1287360
#define WF_TOTAL 1291456

__device__ __forceinline__ float b2f(bf16 x) { return __bfloat162float(x); }
__device__ __forceinline__ float blo(unsigned u) { return __uint_as_float(u << 16); }
__device__ __forceinline__ float bhi(unsigned u) { return __uint_as_float(u & 0xffff0000u); }

// ------------------------------------------------ dtype detection
__global__ void detect_kernel(const void* __restrict__ wedge_raw, int* __restrict__ flag) {
  __shared__ int cnt_sh[256];
  const unsigned short* p = (const unsigned short*)wedge_raw;
  int c = 0;
  for (int i = threadIdx.x; i < 32768; i += 256) {
    float v = __uint_as_float(((unsigned)p[2 * i]) << 16);
    if (fabsf(v) > 4.f) c++;
  }
  cnt_sh[threadIdx.x] = c;
  __syncthreads();
  for (int s = 128; s > 0; s >>= 1) {
    if (threadIdx.x < s) cnt_sh[threadIdx.x] += cnt_sh[threadIdx.x + s];
    __syncthreads();
  }
  if (threadIdx.x == 0) *flag = cnt_sh[0];   // >100 => inputs are f32
}

// ------------------------------------------------ convert all weights -> f32 in ws
__global__ void convert_kernel(const void* s0, const void* s1, const void* s2, const void* s3,
                               const void* s4, const void* s5, const void* s6, const void* s7,
                               const void* s8, const void* s9,
                               const int* __restrict__ flag, float* __restrict__ wf) {
  int i = blockIdx.x * 256 + threadIdx.x;
  if (i >= WF_TOTAL) return;
  const void* src; int local;
  if      (i < OF_WHH)   { src = s0; local = i; }
  else if (i < OF_BIH)   { src = s1; local = i - OF_WHH; }
  else if (i < OF_BHH)   { src = s2; local = i - OF_BIH; }
  else if (i < OF_WP2H)  { src = s3; local = i - OF_BHH; }
  else if (i < OF_BP2H)  { src = s4; local = i - OF_WP2H; }
  else if (i < OF_WUNI)  { src = s5; local = i - OF_BP2H; }
  else if (i < OF_BUNI)  { src = s6; local = i - OF_WUNI; }
  else if (i < OF_WEDGE) { src = s7; local = i - OF_BUNI; }
  else if (i < OF_BEDGE) { src = s8; local = i - OF_WEDGE; }
  else                   { src = s9; local = i - OF_BEDGE; }
  bool isf32 = (*flag) > 100;
  wf[i] = isf32 ? ((const float*)src)[local] : b2f(((const bf16*)src)[local]);
}

// ------------------------------------------------ G1 = emb[tok]@W_ih^T + b_ih + b_hh
// Gate-interleaved output: G1[t][j*4 + gate], so the LSTM reads one float4
// = {i,f,g,o} per h-row.
__global__ __launch_bounds__(512) void g1_kernel(const int* __restrict__ tokens,
                                                 const void* __restrict__ emb_raw,
                                                 const int* __restrict__ flag,
                                                 const float* __restrict__ wf,
                                                 float* __restrict__ G1) {
  __shared__ __attribute__((aligned(16))) float xs[8 * NE];
  const bool isf32 = (*flag) > 100;
  const int t0 = blockIdx.x * 8;
  for (int q = threadIdx.x; q < 8 * NE; q += 512) {
    int tok = q >> 8, e = q & 255;
    size_t off = (size_t)tokens[t0 + tok] * NE + e;
    xs[q] = isf32 ? ((const float*)emb_raw)[off] : b2f(((const bf16*)emb_raw)[off]);
  }
  __syncthreads();
  const int r = threadIdx.x;                 // gate row 0..511
  const float bias = wf[OF_BIH + r] + wf[OF_BHH + r];
  float acc[8];
#pragma unroll
  for (int k = 0; k < 8; ++k) acc[k] = bias;
  const float4* W4 = (const float4*)(wf + OF_WIH + (size_t)r * NE);
#pragma unroll 8
  for (int j = 0; j < 64; ++j) {
    float4 wv = W4[j];
#pragma unroll
    for (int tok = 0; tok < 8; ++tok) {
      float4 xv = ((const float4*)(xs + tok * NE))[j];   // wave-uniform broadcast
      acc[tok] += wv.x * xv.x + wv.y * xv.y + wv.z * xv.z + wv.w * xv.w;
    }
  }
  const int gi = (r & 127) * 4 + (r >> 7);   // gate-interleaved slot
#pragma unroll
  for (int tok = 0; tok < 8; ++tok) G1[(size_t)(t0 + tok) * 512 + gi] = acc[tok];
}

// ------------------------------------------------ sequential LSTM, 1 block, 512 threads
// Model (fits R0/R9/R10): R9's 1990 cyc/step = overlap of LDS-broadcast pipe
// (~1000 cyc: 256 ds_read_b128/step), VALU issue (~880 cyc/SIMD), skeleton
// (~500). Weights ARE register-resident in R9 (VGPR=84 = 64 wt + 20) — no
// L2 term. This version cuts the LDS term 4x: thread r = (h-row j=r>>2,
// k-quarter kq=r&3) computes ALL 4 gate rows of j over 32 k -> h-reads are
// 8 b128/thread = 64 wave-ops/step (was 256). Quad shfl_xor reduce; lane
// kq==0 adds G1 and writes g_sh[j] (float4). Phase B stays in 128 threads
// (R10 proved 8-wave replication costs more VALU than it saves in sync).
__global__ __launch_bounds__(512) void lstm_kernel(const float* __restrict__ wf,
                                                   const void* __restrict__ whh_raw,
                                                   const int* __restrict__ flag,
                                                   const float* __restrict__ G1,
                                                   float* __restrict__ hidden) {
  const int r  = threadIdx.x;                // 0..511
  const int j  = r >> 2;                     // h-row 0..127
  const int kq = r & 3;                      // k-quarter
  __shared__ __attribute__((aligned(16))) float4 g_sh[NH];
  __shared__ __attribute__((aligned(16))) float h_sh[NH];
  const bool isf32 = (*flag) > 100;

  float c = 0.f;
  if (r < NH) h_sh[r] = 0.f;
  __syncthreads();

  if (!isf32) {
    // bf16 weights: 4 gate rows x 32 k = 16 loop-invariant uint4 loads ->
    // LICM hoists into 64 VGPRs (R9-proven pattern).
    const unsigned short* wb = (const unsigned short*)whh_raw;
    const uint4* Wp0 = (const uint4*)(wb + (size_t)(0 * 128 + j) * NH + kq * 32);
    const uint4* Wp1 = (const uint4*)(wb + (size_t)(1 * 128 + j) * NH + kq * 32);
    const uint4* Wp2 = (const uint4*)(wb + (size_t)(2 * 128 + j) * NH + kq * 32);
    const uint4* Wp3 = (const uint4*)(wb + (size_t)(3 * 128 + j) * NH + kq * 32);
    float4 gnext = make_float4(0.f, 0.f, 0.f, 0.f);
    if (kq == 0) gnext = *(const float4*)(G1 + 4 * j);   // prefetch t=0
    for (int t = 0; t < NL; ++t) {
      float4 gcur = gnext;
      if (kq == 0 && t + 1 < NL)
        gnext = *(const float4*)(G1 + (size_t)(t + 1) * 512 + 4 * j);
      const float4* h4 = (const float4*)(h_sh + kq * 32);
      float4 hv0 = h4[0], hv1 = h4[1], hv2 = h4[2], hv3 = h4[3];
      float4 hv4 = h4[4], hv5 = h4[5], hv6 = h4[6], hv7 = h4[7];
      fx2 a0 = {0.f, 0.f}, a1 = {0.f, 0.f}, a2 = {0.f, 0.f}, a3 = {0.f, 0.f};
#define QMAC(i, hA, hB) {                                                   \
      fx2 e01, e23, e45, e67;                                               \
      e01.x = hA.x; e01.y = hA.y; e23.x = hA.z; e23.y = hA.w;               \
      e45.x = hB.x; e45.y = hB.y; e67.x = hB.z; e67.y = hB.w;               \
      { uint4 wq = Wp0[i]; fx2 w01, w23, w45, w67;                          \
        w01.x = blo(wq.x); w01.y = bhi(wq.x); w23.x = blo(wq.y); w23.y = bhi(wq.y); \
        w45.x = blo(wq.z); w45.y = bhi(wq.z); w67.x = blo(wq.w); w67.y = bhi(wq.w); \
        a0 += w01 * e01; a0 += w23 * e23; a0 += w45 * e45; a0 += w67 * e67; } \
      { uint4 wq = Wp1[i]; fx2 w01, w23, w45, w67;                          \
        w01.x = blo(wq.x); w01.y = bhi(wq.x); w23.x = blo(wq.y); w23.y = bhi(wq.y); \
        w45.x = blo(wq.z); w45.y = bhi(wq.z); w67.x = blo(wq.w); w67.y = bhi(wq.w); \
        a1 += w01 * e01; a1 += w23 * e23; a1 += w45 * e45; a1 += w67 * e67; } \
      { uint4 wq = Wp2[i]; fx2 w01, w23, w45, w67;                          \
        w01.x = blo(wq.x); w01.y = bhi(wq.x); w23.x = blo(wq.y); w23.y = bhi(wq.y); \
        w45.x = blo(wq.z); w45.y = bhi(wq.z); w67.x = blo(wq.w); w67.y = bhi(wq.w); \
        a2 += w01 * e01; a2 += w23 * e23; a2 += w45 * e45; a2 += w67 * e67; } \
      { uint4 wq = Wp3[i]; fx2 w01, w23, w45, w67;                          \
        w01.x = blo(wq.x); w01.y = bhi(wq.x); w23.x = blo(wq.y); w23.y = bhi(wq.y); \
        w45.x = blo(wq.z); w45.y = bhi(wq.z); w67.x = blo(wq.w); w67.y = bhi(wq.w); \
        a3 += w01 * e01; a3 += w23 * e23; a3 += w45 * e45; a3 += w67 * e67; } }
      QMAC(0, hv0, hv1)
      QMAC(1, hv2, hv3)
      QMAC(2, hv4, hv5)
      QMAC(3, hv6, hv7)
#undef QMAC
      float s0 = a0.x + a0.y, s1 = a1.x + a1.y, s2 = a2.x + a2.y, s3 = a3.x + a3.y;
      s0 += __shfl_xor(s0, 1); s1 += __shfl_xor(s1, 1);
      s2 += __shfl_xor(s2, 1); s3 += __shfl_xor(s3, 1);
      s0 += __shfl_xor(s0, 2); s1 += __shfl_xor(s1, 2);
      s2 += __shfl_xor(s2, 2); s3 += __shfl_xor(s3, 2);
      if (kq == 0) {
        float4 gf;
        gf.x = s0 + gcur.x; gf.y = s1 + gcur.y;
        gf.z = s2 + gcur.z; gf.w = s3 + gcur.w;
        g_sh[j] = gf;
      }
      __syncthreads();
      if (r < NH) {                          // phase B: row r; gates i,f,g,o
        float4 g = g_sh[r];
        float si = 1.f / (1.f + __expf(-g.x));
        float sf = 1.f / (1.f + __expf(-g.y));
        float tg = 1.f - 2.f / (__expf(2.f * g.z) + 1.f);
        float so = 1.f / (1.f + __expf(-g.w));
        c = sf * c + si * tg;
        float hh = so * (1.f - 2.f / (__expf(2.f * c) + 1.f));
        h_sh[r] = hh;
        hidden[(size_t)(NL - 1 + t) * NH + r] = hh;   // leaf node L-1+t
      }
      __syncthreads();
    }
  } else {
    // f32 weights (correctness path): same structure, streamed from L2.
    const float* base = wf + OF_WHH;
    const float4* Fp0 = (const float4*)(base + (size_t)(0 * 128 + j) * NH + kq * 32);
    const float4* Fp1 = (const float4*)(base + (size_t)(1 * 128 + j) * NH + kq * 32);
    const float4* Fp2 = (const float4*)(base + (size_t)(2 * 128 + j) * NH + kq * 32);
    const float4* Fp3 = (const float4*)(base + (size_t)(3 * 128 + j) * NH + kq * 32);
    float4 gnext = make_float4(0.f, 0.f, 0.f, 0.f);
    if (kq == 0) gnext = *(const float4*)(G1 + 4 * j);
    for (int t = 0; t < NL; ++t) {
      float4 gcur = gnext;
      if (kq == 0 && t + 1 < NL)
        gnext = *(const float4*)(G1 + (size_t)(t + 1) * 512 + 4 * j);
      const float4* h4 = (const float4*)(h_sh + kq * 32);
      float s0 = 0.f, s1 = 0.f, s2 = 0.f, s3 = 0.f;
#pragma unroll
      for (int i = 0; i < 8; ++i) {
        float4 hq = h4[i];
        float4 w0 = Fp0[i], w1 = Fp1[i], w2 = Fp2[i], w3 = Fp3[i];
        s0 += w0.x * hq.x + w0.y * hq.y + w0.z * hq.z + w0.w * hq.w;
        s1 += w1.x * hq.x + w1.y * hq.y + w1.z * hq.z + w1.w * hq.w;
        s2 += w2.x * hq.x + w2.y * hq.y + w2.z * hq.z + w2.w * hq.w;
        s3 += w3.x * hq.x + w3.y * hq.y + w3.z * hq.z + w3.w * hq.w;
      }
      s0 += __shfl_xor(s0, 1); s1 += __shfl_xor(s1, 1);
      s2 += __shfl_xor(s2, 1); s3 += __shfl_xor(s3, 1);
      s0 += __shfl_xor(s0, 2); s1 += __shfl_xor(s1, 2);
      s2 += __shfl_xor(s2, 2); s3 += __shfl_xor(s3, 2);
      if (kq == 0) {
        float4 gf;
        gf.x = s0 + gcur.x; gf.y = s1 + gcur.y;
        gf.z = s2 + gcur.z; gf.w = s3 + gcur.w;
        g_sh[j] = gf;
      }
      __syncthreads();
      if (r < NH) {
        float4 g = g_sh[r];
        float si = 1.f / (1.f + __expf(-g.x));
        float sf = 1.f / (1.f + __expf(-g.y));
        float tg = 1.f - 2.f / (__expf(2.f * g.z) + 1.f);
        float so = 1.f / (1.f + __expf(-g.w));
        c = sf * c + si * tg;
        float hh = so * (1.f - 2.f / (__expf(2.f * c) + 1.f));
        h_sh[r] = hh;
        hidden[(size_t)(NL - 1 + t) * NH + r] = hh;
      }
      __syncthreads();
    }
  }
}

// ------------------------------------------------ one tree level: pair -> parent hidden
__global__ void p2h_kernel(const float* __restrict__ wf, float* __restrict__ hidden, int base) {
  int node = base + blockIdx.x;
  int j = threadIdx.x;                       // 128
  __shared__ __attribute__((aligned(16))) float pr[2 * NH];
  const float* hl = hidden + (size_t)(2 * node + 1) * NH;  // children contiguous
  pr[j] = hl[j];
  pr[j + NH] = hl[j + NH];
  __syncthreads();
  float acc = wf[OF_BP2H + j];
  const float4* W4 = (const float4*)(wf + OF_WP2H + (size_t)j * 2 * NH);
  const float4* p4 = (const float4*)pr;
#pragma unroll 16
  for (int q = 0; q < 64; ++q) {
    float4 u = W4[q], x = p4[q];
    acc += u.x * x.x + u.y * x.y + u.z * x.z + u.w * x.w;
  }
  hidden[(size_t)node * NH + j] = acc;
}

// ------------------------------------------------ unary = hidden@W_uni^T + b; zero f2n[0]
__global__ void unary_kernel(const float* __restrict__ wf, const float* __restrict__ hidden,
                             float* __restrict__ unary, float* __restrict__ f2n) {
  int node = blockIdx.x;
  int ct = threadIdx.x;                      // 64
  __shared__ __attribute__((aligned(16))) float hs[NH];
  hs[ct] = hidden[(size_t)node * NH + ct];
  hs[ct + 64] = hidden[(size_t)node * NH + 64 + ct];
  __syncthreads();
  float acc = wf[OF_BUNI + ct];
  const float4* W4 = (const float4*)(wf + OF_WUNI + (size_t)ct * NH);
  const float4* h4 = (const float4*)hs;
#pragma unroll
  for (int q = 0; q < 32; ++q) {
    float4 u = W4[q], x = h4[q];
    acc += u.x * x.x + u.y * x.y + u.z * x.z + u.w * x.w;
  }
  unary[(size_t)node * NT + ct] = acc;
  if (node == 0) f2n[ct] = 0.f;              // root gets no top-factor message
}

// ------------------------------------------------ edge_fac GEMM: [8192,256]x[256,4096]
__global__ __launch_bounds__(256) void edge_kernel(const float* __restrict__ hidden,
                                                   const float* __restrict__ wf,
                                                   float* __restrict__ edge) {
  __shared__ __attribute__((aligned(16))) float As[32][132];  // [k][m]
  __shared__ __attribute__((aligned(16))) float Bs[32][132];  // [k][n]
  const int tid = threadIdx.x;
  const int nb = blockIdx.x;                 // 0..31 (N tile of 128)
  const int mb = blockIdx.y;                 // 0..63 (M tile of 128)
  const int tm = tid >> 4, tn = tid & 15;    // 16x16 threads, 8x8 micro (split 4+4)
  float acc[8][8];
#pragma unroll
  for (int i = 0; i < 8; ++i)
#pragma unroll
    for (int j = 0; j < 8; ++j) acc[i][j] = 0.f;
  const int sr = tid >> 1;                   // staging row 0..127
  const int sq = tid & 1;                    // which 16-k half
  for (int ch = 0; ch < 8; ++ch) {           // K chunks of 32
    {                                        // stage A
      int gm = mb * 128 + sr;
      const float* srcA = (ch < 4) ? hidden + (size_t)(gm >> 1) * NH + ch * 32
                                   : hidden + (size_t)(gm + 1) * NH + (ch - 4) * 32;
      bool ok = (gm < NNODE - 1);
#pragma unroll
      for (int i = 0; i < 4; ++i) {
        int kk = sq * 16 + i * 4;
        float4 v = ok ? *(const float4*)(srcA + kk) : make_float4(0.f, 0.f, 0.f, 0.f);
        As[kk + 0][sr] = v.x; As[kk + 1][sr] = v.y; As[kk + 2][sr] = v.z; As[kk + 3][sr] = v.w;
      }
    }
    {                                        // stage B
      int gn = nb * 128 + sr;                // < 4096 always
      const float* srcB = wf + OF_WEDGE + (size_t)gn * NE + ch * 32;
#pragma unroll
      for (int i = 0; i < 4; ++i) {
        int kk = sq * 16 + i * 4;
        float4 v = *(const float4*)(srcB + kk);
        Bs[kk + 0][sr] = v.x; Bs[kk + 1][sr] = v.y; Bs[kk + 2][sr] = v.z; Bs[kk + 3][sr] = v.w;
      }
    }
    __syncthreads();
#pragma unroll 8
    for (int kk = 0; kk < 32; ++kk) {
      float a[8], b[8];
      *(float4*)(a)     = *(const float4*)&As[kk][tm * 4];
      *(float4*)(a + 4) = *(const float4*)&As[kk][64 + tm * 4];
      *(float4*)(b)     = *(const float4*)&Bs[kk][tn * 4];
      *(float4*)(b + 4) = *(const float4*)&Bs[kk][64 + tn * 4];
#pragma unroll
      for (int i = 0; i < 8; ++i)
#pragma unroll
        for (int j = 0; j < 8; ++j) acc[i][j] += a[i] * b[j];
    }
    __syncthreads();
  }
  float bias[8];
#pragma unroll
  for (int j = 0; j < 8; ++j)
    bias[j] = wf[OF_BEDGE + nb * 128 + (j >> 2) * 64 + tn * 4 + (j & 3)];
#pragma unroll
  for (int i = 0; i < 8; ++i) {
    int gm = mb * 128 + (i >> 2) * 64 + tm * 4 + (i & 3);
    if (gm < NNODE - 1) {
      float* row = edge + (size_t)gm * 4096 + nb * 128;
      float4 o0, o1;
      o0.x = acc[i][0] + bias[0]; o0.y = acc[i][1] + bias[1];
      o0.z = acc[i][2] + bias[2]; o0.w = acc[i][3] + bias[3];
      o1.x = acc[i][4] + bias[4]; o1.y = acc[i][5] + bias[5];
      o1.z = acc[i][6] + bias[6]; o1.w = acc[i][7] + bias[7];
      *(float4*)(row + tn * 4) = o0;
      *(float4*)(row + 64 + tn * 4) = o1;
    }
  }
}

// ------------------------------------------------ upward level
__global__ void up_kernel(const float* __restrict__ unary, const float* __restrict__ edge,
                          float* __restrict__ v2f, float* __restrict__ f2p,
                          int base, int depth) {
  int node = base + blockIdx.x;
  int tid = threadIdx.x;                     // 64; tid = p (parent tag)
  __shared__ __attribute__((aligned(16))) float vs[NT];
  float vv = unary[(size_t)node * NT + tid];
  if (depth < NDEPTH)
    vv += f2p[(size_t)(2 * node + 1) * NT + tid] + f2p[(size_t)(2 * node + 2) * NT + tid];
  v2f[(size_t)node * NT + tid] = vv;
  vs[tid] = vv;
  __syncthreads();
  if (depth == 0) return;
  const float4* E4 = (const float4*)(edge + (size_t)(node - 1) * 4096 + tid * 64);
  const float4* v4 = (const float4*)vs;
  float x[NT];
#pragma unroll
  for (int q = 0; q < 16; ++q) {
    float4 e = E4[q], vq = v4[q];
    x[4 * q + 0] = e.x + vq.x; x[4 * q + 1] = e.y + vq.y;
    x[4 * q + 2] = e.z + vq.z; x[4 * q + 3] = e.w + vq.w;
  }
  float m = x[0];
#pragma unroll
  for (int i = 1; i < NT; ++i) m = fmaxf(m, x[i]);
  float s = 0.f;
#pragma unroll
  for (int i = 0; i < NT; ++i) s += __expf(x[i] - m);
  f2p[(size_t)node * NT + tid] = m + __logf(s);
}

// ------------------------------------------------ downward level
__global__ void down_kernel(const float* __restrict__ unary, const float* __restrict__ edge,
                            const float* __restrict__ f2p, float* __restrict__ f2n,
                            int base) {
  int node = base + blockIdx.x;
  int tid = threadIdx.x;                     // 64; tid = c (child tag)
  int par = (node - 1) >> 1;
  int sib = (node & 1) ? node + 1 : node - 1;
  __shared__ __attribute__((aligned(16))) float us[NT];
  us[tid] = unary[(size_t)par * NT + tid] + f2n[(size_t)par * NT + tid] +
            f2p[(size_t)sib * NT + tid];
  __syncthreads();
  float uu[NT];
  const float4* u4 = (const float4*)us;
#pragma unroll
  for (int q = 0; q < 16; ++q) {
    float4 t4 = u4[q];
    uu[4 * q] = t4.x; uu[4 * q + 1] = t4.y; uu[4 * q + 2] = t4.z; uu[4 * q + 3] = t4.w;
  }
  const float* E = edge + (size_t)(node - 1) * 4096 + tid;
  float x[NT];
#pragma unroll
  for (int p = 0; p < NT; ++p) x[p] = E[(size_t)p * 64] + uu[p];
  float m = x[0];
#pragma unroll
  for (int i = 1; i < NT; ++i) m = fmaxf(m, x[i]);
  float s = 0.f;
#pragma unroll
  for (int i = 0; i < NT; ++i) s += __expf(x[i] - m);
  f2n[(size_t)node * NT + tid] = m + __logf(s);
}

// ------------------------------------------------ beliefs -> postorder -> out (flag dtype)
__global__ void final_kernel(const float* __restrict__ v2f, const float* __restrict__ f2n,
                             const int* __restrict__ flag, void* __restrict__ out) {
  int node = blockIdx.x;
  int tid = threadIdx.x;                     // 64
  unsigned v = (unsigned)node + 1u;
  int d = 31 - __clz((int)v);
  int b0 = 0, S = NNODE;
  for (int b = d - 1; b >= 0; --b) {
    int sz = (S - 1) >> 1;
    if ((v >> b) & 1) b0 += sz;
    S = sz;
  }
  int pos = b0 + S - 1;
  float val = v2f[(size_t)node * NT + tid] + f2n[(size_t)node * NT + tid];
  if ((*flag) > 100) ((float*)out)[(size_t)pos * NT + tid] = val;
  else               ((bf16*)out)[(size_t)pos * NT + tid] = __float2bfloat16(val);
}

// ------------------------------------------------
extern "C" void kernel_launch(void* const* d_in, const int* in_sizes, int n_in,
                              void* d_out, int out_size, void* d_ws, size_t ws_size,
                              hipStream_t stream) {
  (void)in_sizes; (void)n_in; (void)out_size; (void)ws_size;
  const int* tokens = (const int*)d_in[0];

  // workspace layout (floats); ~160.3 MB total
  float* ws     = (float*)d_ws;
  int*   flag   = (int*)ws;                            // [16]
  float* wf     = ws + 16;                             // converted f32 weights
  float* hidden = wf + WF_TOTAL;                       // [8191][128]
  float* G1     = hidden + (size_t)NNODE * NH;         // [4096][512] gate-interleaved
  float* unary  = G1 + (size_t)NL * 512;               // [8191][64]
  float* v2f    = unary + (size_t)NNODE * NT;          // [8191][64]
  float* f2p    = v2f + (size_t)NNODE * NT;            // [8191][64]
  float* f2n    = f2p + (size_t)NNODE * NT;            // [8191][64]
  float* edge   = f2n + (size_t)NNODE * NT;            // [8190][4096]

  detect_kernel<<<1, 256, 0, stream>>>(d_in[10], flag);
  convert_kernel<<<(WF_TOTAL + 255) / 256, 256, 0, stream>>>(
      d_in[2], d_in[3], d_in[4], d_in[5], d_in[6], d_in[7],
      d_in[8], d_in[9], d_in[10], d_in[11], flag, wf);
  g1_kernel<<<NL / 8, 512, 0, stream>>>(tokens, d_in[1], flag, wf, G1);
  lstm_kernel<<<1, 512, 0, stream>>>(wf, d_in[3], flag, G1, hidden);
  for (int d = NDEPTH - 1; d >= 0; --d)
    p2h_kernel<<<1 << d, 128, 0, stream>>>(wf, hidden, (1 << d) - 1);
  unary_kernel<<<NNODE, 64, 0, stream>>>(wf, hidden, unary, f2n);
  edge_kernel<<<dim3(32, 64), 256, 0, stream>>>(hidden, wf, edge);
  for (int d = NDEPTH; d >= 0; --d)
    up_kernel<<<1 << d, 64, 0, stream>>>(unary, edge, v2f, f2p, (1 << d) - 1, d);
  for (int d = 1; d <= NDEPTH; ++d)
    down_kernel<<<1 << d, 64, 0, stream>>>(unary, edge, f2p, f2n, (1 << d) - 1);
  final_kernel<<<NNODE, 64, 0, stream>>>(v2f, f2n, flag, d_out);
}